// Round 10
// baseline (236.106 us; speedup 1.0000x reference)
//
#include <hip/hip_runtime.h>
#include <hip/hip_fp16.h>
#include <cfloat>

// NearestNeighborGraph: S=16, N=2048, D=64, K=16.
// Round-18: 1.5-pass scan with robust tau0 + unconditional overflow fallback.
//  r17 post-mortem: ring overflow. tau0 from a 4th-of-128 prefix is too
//  noisy (P(overflow) ~ 1e-3/row x 32768 rows ~ 100 corrupted rows).
//  Fixes:
//   - NJT0 16 (tau0 = max_w 4th-of-256 + MARGIN): overflow P ~ 1e-14.
//   - RCAP 176 (LDS 40320B, still 4 blocks/CU).
//   - rescue: if rcnt[row] > RCAP the row's 8 workers IGNORE the ring and
//     exact-brute-force the full 2048 j's (bit-exact fp32 chains, lex
//     top-16 == reference) -> correctness unconditional on tau0 quality.
//  Scan volume: 48 tiles/wave vs r16's 64 (0.75x).
//  tau_final fold order unchanged -> bit-identical to r16 (passed);
//  A2 filter tau0 >= tau_final -> candidate superset; exact rescue
//  discards extras -> output identical.

typedef _Float16 half8 __attribute__((ext_vector_type(8)));
typedef _Float16 half4 __attribute__((ext_vector_type(4)));
typedef float    f32x4 __attribute__((ext_vector_type(4)));

constexpr int NS = 16, NP = 2048, ND = 64, KK = 16;
constexpr int NWV = 4;              // waves per block
constexpr int NT  = NWV * 64;       // 256 threads
constexpr int RB  = 32;             // rows (i) per block
constexpr int ITN = RB / 16;        // 2 i-tiles
constexpr int JW  = NP / NWV;       // 512 j per wave
constexpr int NJT = JW / 16;        // 32 j-tiles per wave
constexpr int NJT0 = 16;            // prefix tiles (tau0 seed + B' rescan)
constexpr int PF  = 4;              // pipeline depth (static reg slots)
constexpr int MS  = 17;             // merge-tree stride
constexpr int RCAP = 176;           // candidate ring slots per row
constexpr int RSTR = RCAP + 1;      // ring stride
constexpr float MARGIN = 1.0f;

// ---- prep: 16 rows/block; coalesced f16 copy + rotated-chain x2 ----
__global__ __launch_bounds__(256)
void prep_kernel(const float* __restrict__ h, float* __restrict__ x2,
                 _Float16* __restrict__ hh)
{
    const int b = blockIdx.x;                 // 0..2047, 16 rows each
    const int t = threadIdx.x;
    const size_t base = (size_t)b * 16 * ND;  // flat float offset

    // f16 conversion: thread t -> elements [base + 4t, base + 4t + 4)
    float4 v = *(const float4*)(h + base + (size_t)t * 4);
    half4 p;
    p[0] = (_Float16)v.x; p[1] = (_Float16)v.y;
    p[2] = (_Float16)v.z; p[3] = (_Float16)v.w;
    *(half4*)(hh + base + (size_t)t * 4) = p;

    // x2: rotated chain, bit-identical to rounds 1-17 (1 thread per row)
    if (t < 16) {
        const int g = b * 16 + t;             // flat row
        const float4* row = (const float4*)(h + (size_t)g * ND);
        const int ph = g & 15;
        float a0 = 0.f, a1 = 0.f, a2 = 0.f, a3 = 0.f;
        #pragma unroll
        for (int k = 0; k < 16; ++k) {
            float4 u = row[(k + ph) & 15];
            a0 = fmaf(u.x, u.x, a0); a1 = fmaf(u.y, u.y, a1);
            a2 = fmaf(u.z, u.z, a2); a3 = fmaf(u.w, u.w, a3);
        }
        x2[g] = (a0 + a1) + (a2 + a3);
    }
}

// lexicographic (d2, j) insert == top_k tie-break (lowest index on equal d2)
__device__ __forceinline__ bool lexlt(float a, int ja, float b, int jb)
{
    return (a < b) || (a == b && ja < jb);
}
__device__ __forceinline__ void insert16x(float (&d)[KK], int (&ix)[KK],
                                          float v, int j)
{
    #pragma unroll
    for (int p = KK - 1; p > 0; --p) {
        bool sh = lexlt(v, j, d[p - 1], ix[p - 1]);
        bool he = lexlt(v, j, d[p], ix[p]);
        float nd = sh ? d[p - 1] : (he ? v : d[p]);
        int   ni = sh ? ix[p - 1] : (he ? j : ix[p]);
        d[p] = nd; ix[p] = ni;
    }
    if (lexlt(v, j, d[0], ix[0])) { d[0] = v; ix[0] = j; }
}

// in-place bitonic merge of two sorted-4 lists across lane-xor 'mask'
__device__ __forceinline__ void bitonic4(float &a1, float &a2, float &a3,
                                         float &a4, int mask)
{
    float b1 = __shfl_xor(a1, mask), b2 = __shfl_xor(a2, mask);
    float b3 = __shfl_xor(a3, mask), b4 = __shfl_xor(a4, mask);
    float m1 = fminf(a1, b4), m2 = fminf(a2, b3);
    float m3 = fminf(a3, b2), m4 = fminf(a4, b1);
    float u1 = fminf(m1, m3), u3 = fmaxf(m1, m3);
    float u2 = fminf(m2, m4), u4 = fmaxf(m2, m4);
    a1 = fminf(u1, u2); a2 = fmaxf(u1, u2);
    a3 = fminf(u3, u4); a4 = fmaxf(u3, u4);
}

__global__ __launch_bounds__(NT, 4)
void knn_mfma(const float* __restrict__ h, const _Float16* __restrict__ hh,
              const float* __restrict__ x2g, float* __restrict__ out)
{
    // 10080 floats = 40320 B -> 4 blocks/CU (4 x 40448 rounded = 161792 <= 163840)
    __shared__ __align__(16) float smem[10080];
    float* ldsx2  = smem;                    // [0,2048)
    float* mw     = smem + 2048;             // [2048,2176)  4 waves x 32 rows
    float* ldsthr = smem + 2176;             // [2176,2208)
    int*   rcnt   = (int*)(smem + 2208);     // [2208,2240)
    int*   ring   = (int*)(smem + 2240);     // [2240,7904)  32 x 177
    float* md     = smem + 7904;             // [7904,8992)  2 x 32 x 17
    int*   mi     = (int*)(smem + 8992);     // [8992,10080)

    const int t   = threadIdx.x;
    const int ln  = t & 63;
    const int qd  = ln >> 4;                 // j-subslice within wave
    const int cl  = ln & 15;                 // i within 16-tile (swapped D col)
    const int q   = t >> 6;                  // wave id (j-quarter)
    const int row = ln & 31;                 // lane's rescue row
    const int jh  = ln >> 5;                 // rescue worker split
    // XCD sample-affinity swizzle (bijective): sample s -> XCD (s&7),
    // assuming hardware round-robin bid->XCD bid%8 (perf heuristic only).
    const int bid = blockIdx.x;
    const int xcd = bid & 7;
    const int kb  = bid >> 3;                // 0..127
    const int s   = xcd + ((kb & 1) << 3);   // 0..15
    const int rb  = kb >> 1;                 // 0..63
    const int rowbase = rb * RB;             // block's 32 i-rows (sample-local)
    const float*    __restrict__ hs  = h  + (size_t)s * NP * ND;
    const _Float16* __restrict__ hhs = hh + (size_t)s * NP * ND;

    // stage sample x2; init ring counts
    ((float4*)ldsx2)[t]       = ((const float4*)(x2g + s * NP))[t];
    ((float4*)ldsx2)[t + 256] = ((const float4*)(x2g + s * NP))[t + 256];
    if (t < RB) rcnt[t] = 0;

    // i-fragments (the MFMA *B* operand): lane holds I[n=cl][k=qd*8..+7]
    half8 ifr[ITN][2];
    #pragma unroll
    for (int it = 0; it < ITN; ++it) {
        const _Float16* ap = hhs + (size_t)(rowbase + it * 16 + cl) * ND + qd * 8;
        ifr[it][0] = *(const half8*)(ap);
        ifr[it][1] = *(const half8*)(ap + 32);
    }
    __syncthreads();

    const int jbase = q * JW;
    const _Float16* __restrict__ jrow0 = hhs + (size_t)(jbase + cl) * ND + qd * 8;

    auto loadj = [&](int jt, half8 &lo, half8 &hi, f32x4 &xq) {
        const _Float16* bp = jrow0 + (size_t)jt * (16 * ND);
        lo = *(const half8*)(bp);
        hi = *(const half8*)(bp + 32);
        xq = *(const f32x4*)(ldsx2 + jbase + jt * 16 + qd * 4);
    };

    // fold state: per-lane sorted top-4 of d2' = x2j - 2*dot
    float t1[ITN], t2[ITN], t3[ITN], t4[ITN];
    #pragma unroll
    for (int it = 0; it < ITN; ++it)
        { t1[it] = FLT_MAX; t2[it] = FLT_MAX; t3[it] = FLT_MAX; t4[it] = FLT_MAX; }
    float thrv[ITN];

    // ===== A1: tiles [0, NJT0) — fold only ==================================
    {
        half8 plo[PF], phi[PF]; f32x4 pxq[PF];
        #pragma unroll
        for (int p = 0; p < PF; ++p) loadj(p, plo[p], phi[p], pxq[p]);

        for (int t0 = 0; t0 < NJT0; t0 += PF) {
            #pragma unroll
            for (int p = 0; p < PF; ++p) {
                half8 clo = plo[p], chi = phi[p]; f32x4 cxq = pxq[p];
                int nx = t0 + p + PF;
                if (nx < NJT0) loadj(nx, plo[p], phi[p], pxq[p]);
                #pragma unroll
                for (int it = 0; it < ITN; ++it) {
                    f32x4 acc;
                    acc = __builtin_amdgcn_mfma_f32_16x16x32_f16(
                              clo, ifr[it][0], (f32x4){0.f, 0.f, 0.f, 0.f}, 0, 0, 0);
                    acc = __builtin_amdgcn_mfma_f32_16x16x32_f16(
                              chi, ifr[it][1], acc, 0, 0, 0);
                    #pragma unroll
                    for (int r = 0; r < 4; ++r) {
                        float v  = fmaf(-2.f, acc[r], cxq[r]);
                        float n1 = fminf(t1[it], v);
                        float n2 = __builtin_amdgcn_fmed3f(t1[it], t2[it], v);
                        float n3 = __builtin_amdgcn_fmed3f(t2[it], t3[it], v);
                        float n4 = __builtin_amdgcn_fmed3f(t3[it], t4[it], v);
                        t1[it] = n1; t2[it] = n2; t3[it] = n3; t4[it] = n4;
                    }
                }
            }
        }
    }

    // ---- mid-merge on COPIES (fold regs untouched) -> tau0 ----
    {
        float c1[ITN], c2[ITN], c3[ITN], c4[ITN];
        #pragma unroll
        for (int it = 0; it < ITN; ++it)
            { c1[it] = t1[it]; c2[it] = t2[it]; c3[it] = t3[it]; c4[it] = t4[it]; }
        #pragma unroll
        for (int it = 0; it < ITN; ++it) {
            bitonic4(c1[it], c2[it], c3[it], c4[it], 16);
            bitonic4(c1[it], c2[it], c3[it], c4[it], 32);
        }
        if (qd == 0) {
            mw[q * 32 + cl]      = c4[0];   // exact 4th of wave's 256-prefix
            mw[q * 32 + 16 + cl] = c4[1];
        }
    }
    __syncthreads();
    if (q == 0 && ln < 32) {
        float m0 = mw[row], m1 = mw[32 + row];
        float m2 = mw[64 + row], m3 = mw[96 + row];
        ldsthr[row] = fmaxf(fmaxf(m0, m1), fmaxf(m2, m3)) + MARGIN;  // tau0
    }
    __syncthreads();
    #pragma unroll
    for (int it = 0; it < ITN; ++it) thrv[it] = ldsthr[it * 16 + cl];

    // ===== A2: tiles [NJT0, NJT) — fold + push d2' < tau0 ===================
    {
        half8 plo[PF], phi[PF]; f32x4 pxq[PF];
        #pragma unroll
        for (int p = 0; p < PF; ++p) loadj(NJT0 + p, plo[p], phi[p], pxq[p]);

        for (int t0 = NJT0; t0 < NJT; t0 += PF) {
            #pragma unroll
            for (int p = 0; p < PF; ++p) {
                half8 clo = plo[p], chi = phi[p]; f32x4 cxq = pxq[p];
                const int j0 = jbase + (t0 + p) * 16;
                int nx = t0 + p + PF;
                if (nx < NJT) loadj(nx, plo[p], phi[p], pxq[p]);
                #pragma unroll
                for (int it = 0; it < ITN; ++it) {
                    f32x4 acc;
                    acc = __builtin_amdgcn_mfma_f32_16x16x32_f16(
                              clo, ifr[it][0], (f32x4){0.f, 0.f, 0.f, 0.f}, 0, 0, 0);
                    acc = __builtin_amdgcn_mfma_f32_16x16x32_f16(
                              chi, ifr[it][1], acc, 0, 0, 0);
                    #pragma unroll
                    for (int r = 0; r < 4; ++r) {
                        float v  = fmaf(-2.f, acc[r], cxq[r]);
                        if (v < thrv[it]) {
                            int rw = it * 16 + cl;
                            int slot = atomicAdd(&rcnt[rw], 1);
                            if (slot < RCAP) ring[rw * RSTR + slot] = j0 + qd * 4 + r;
                        }
                        float n1 = fminf(t1[it], v);
                        float n2 = __builtin_amdgcn_fmed3f(t1[it], t2[it], v);
                        float n3 = __builtin_amdgcn_fmed3f(t2[it], t3[it], v);
                        float n4 = __builtin_amdgcn_fmed3f(t3[it], t4[it], v);
                        t1[it] = n1; t2[it] = n2; t3[it] = n3; t4[it] = n4;
                    }
                }
            }
        }
    }

    // ---- final merge (destructive, == r16) -> tau_final ----
    #pragma unroll
    for (int it = 0; it < ITN; ++it) {
        bitonic4(t1[it], t2[it], t3[it], t4[it], 16);
        bitonic4(t1[it], t2[it], t3[it], t4[it], 32);
    }
    if (qd == 0) {
        mw[q * 32 + cl]      = t4[0];   // exact 4th of wave's 512
        mw[q * 32 + 16 + cl] = t4[1];
    }
    __syncthreads();
    if (q == 0 && ln < 32) {
        float m0 = mw[row], m1 = mw[32 + row];
        float m2 = mw[64 + row], m3 = mw[96 + row];
        ldsthr[row] = fmaxf(fmaxf(m0, m1), fmaxf(m2, m3)) + MARGIN;  // tau
    }
    __syncthreads();
    #pragma unroll
    for (int it = 0; it < ITN; ++it) thrv[it] = ldsthr[it * 16 + cl];

    // ===== B': re-scan tiles [0, NJT0) — push d2' < tau_final ===============
    {
        half8 plo[PF], phi[PF]; f32x4 pxq[PF];
        #pragma unroll
        for (int p = 0; p < PF; ++p) loadj(p, plo[p], phi[p], pxq[p]);

        for (int t0 = 0; t0 < NJT0; t0 += PF) {
            #pragma unroll
            for (int p = 0; p < PF; ++p) {
                half8 clo = plo[p], chi = phi[p]; f32x4 cxq = pxq[p];
                const int j0 = jbase + (t0 + p) * 16;
                int nx = t0 + p + PF;
                if (nx < NJT0) loadj(nx, plo[p], phi[p], pxq[p]);
                #pragma unroll
                for (int it = 0; it < ITN; ++it) {
                    f32x4 acc;
                    acc = __builtin_amdgcn_mfma_f32_16x16x32_f16(
                              clo, ifr[it][0], (f32x4){0.f, 0.f, 0.f, 0.f}, 0, 0, 0);
                    acc = __builtin_amdgcn_mfma_f32_16x16x32_f16(
                              chi, ifr[it][1], acc, 0, 0, 0);
                    #pragma unroll
                    for (int r = 0; r < 4; ++r) {
                        float d2 = fmaf(-2.f, acc[r], cxq[r]);
                        if (d2 < thrv[it]) {
                            int rw = it * 16 + cl;
                            int slot = atomicAdd(&rcnt[rw], 1);
                            if (slot < RCAP) ring[rw * RSTR + slot] = j0 + qd * 4 + r;
                        }
                    }
                }
            }
        }
    }
    __syncthreads();

    // ========== rescue: exact fp32 recompute of candidates ===============
    // row = ln&31; 8 workers per row: (wave q, half jh) take slots w8, w8+8,...
    const int myrow = rowbase + row;
    float4 A[16];
    {
        const float4* ra = (const float4*)(hs + (size_t)myrow * ND);
        #pragma unroll
        for (int k = 0; k < 16; ++k) A[k] = ra[k];
    }
    float x2i;   // ascending chain (exact round-1 i-side value)
    {
        float a0 = 0.f, a1 = 0.f, a2 = 0.f, a3 = 0.f;
        #pragma unroll
        for (int k = 0; k < 16; ++k) {
            a0 = fmaf(A[k].x, A[k].x, a0); a1 = fmaf(A[k].y, A[k].y, a1);
            a2 = fmaf(A[k].z, A[k].z, a2); a3 = fmaf(A[k].w, A[k].w, a3);
        }
        x2i = (a0 + a1) + (a2 + a3);
    }
    float dist[KK]; int idx[KK];
    #pragma unroll
    for (int k = 0; k < KK; ++k) { dist[k] = FLT_MAX; idx[k] = 0; }

    const int rawc = rcnt[row];
    const int w8 = q * 2 + jh;
    if (rawc <= RCAP) {
        // normal path: exact recompute of ring candidates
        #pragma unroll 1
        for (int k = w8; k < rawc; k += 8) {
            int j = ring[row * RSTR + k];
            const float4* cv = (const float4*)(hs + (size_t)j * ND);
            float a0 = 0.f, a1 = 0.f, a2 = 0.f, a3 = 0.f;
            #pragma unroll
            for (int kk = 0; kk < 16; ++kk) {
                float4 c = cv[kk];
                a0 = fmaf(A[kk].x, c.x, a0); a1 = fmaf(A[kk].y, c.y, a1);
                a2 = fmaf(A[kk].z, c.z, a2); a3 = fmaf(A[kk].w, c.w, a3);
            }
            float dotv = (a0 + a1) + (a2 + a3);
            float d2 = fmaf(-2.0f, dotv, x2i + ldsx2[j]);
            if (lexlt(d2, j, dist[KK - 1], idx[KK - 1]))
                insert16x(dist, idx, d2, j);
        }
    } else {
        // overflow fallback (P ~ 1e-14/row): ring is incomplete -> exact
        // brute-force of the full row (reference by construction). Ring
        // entries are SKIPPED entirely (mixing would double-insert).
        #pragma unroll 1
        for (int j = w8; j < NP; j += 8) {
            const float4* cv = (const float4*)(hs + (size_t)j * ND);
            float a0 = 0.f, a1 = 0.f, a2 = 0.f, a3 = 0.f;
            #pragma unroll
            for (int kk = 0; kk < 16; ++kk) {
                float4 c = cv[kk];
                a0 = fmaf(A[kk].x, c.x, a0); a1 = fmaf(A[kk].y, c.y, a1);
                a2 = fmaf(A[kk].z, c.z, a2); a3 = fmaf(A[kk].w, c.w, a3);
            }
            float dotv = (a0 + a1) + (a2 + a3);
            float d2 = fmaf(-2.0f, dotv, x2i + ldsx2[j]);
            if (lexlt(d2, j, dist[KK - 1], idx[KK - 1]))
                insert16x(dist, idx, d2, j);
        }
    }

    // ---- final exact merge (lex): shuffle level + 2 LDS levels (gated) ----
    #pragma unroll 1
    for (int k = 0; k < KK; ++k) {
        float v  = __shfl(dist[k], row + 32);
        int   jv = __shfl(idx[k],  row + 32);
        bool need = (ln < 32) && lexlt(v, jv, dist[KK - 1], idx[KK - 1]);
        if (!__any(need)) break;
        if (need) insert16x(dist, idx, v, jv);
    }
    __syncthreads();
    #pragma unroll 1
    for (int lvl = 0; lvl < 2; ++lvl) {
        const int step = 1 << lvl;
        const int m    = (step << 1) - 1;
        const bool pub = ((q & m) == step) && ln < 32;
        const int reg  = q >> (lvl + 1);
        if (pub) {
            #pragma unroll
            for (int k = 0; k < KK; ++k) {
                md[(reg * RB + row) * MS + k] = dist[k];
                mi[(reg * RB + row) * MS + k] = idx[k];
            }
        }
        __syncthreads();
        if ((q & m) == 0) {
            #pragma unroll 1
            for (int k = 0; k < KK; ++k) {
                float v  = md[(reg * RB + row) * MS + k];
                int   jv = mi[(reg * RB + row) * MS + k];
                bool need = (ln < 32) && lexlt(v, jv, dist[KK - 1], idx[KK - 1]);
                if (!__any(need)) break;
                if (need) insert16x(dist, idx, v, jv);
            }
        }
        __syncthreads();
    }

    // ---- output (wave 0, lower half) ----
    if (q == 0 && ln < 32) {
        const int off = s * NP;
        const size_t rg = (size_t)off + myrow;
        float* o0 = out + rg * KK;
        float* o1 = out + (size_t)NS * NP * KK + rg * KK;
        float* o2 = out + (size_t)2 * NS * NP * KK + rg * KK;
        #pragma unroll
        for (int k = 0; k < KK; ++k) o0[k] = dist[k];
        #pragma unroll
        for (int k = 0; k < KK; ++k) o1[k] = (float)(idx[k] + off);
        #pragma unroll
        for (int k = 0; k < KK; ++k) o2[k] = (float)(off + myrow);
    }
}

extern "C" void kernel_launch(void* const* d_in, const int* in_sizes, int n_in,
                              void* d_out, int out_size, void* d_ws, size_t ws_size,
                              hipStream_t stream)
{
    const float* h = (const float*)d_in[0];
    float* out = (float*)d_out;
    float*    x2 = (float*)d_ws;                     // 32768 floats (128 KB)
    _Float16* hh = (_Float16*)(x2 + NS * NP);        // 16*2048*64 halves (4 MB)

    hipLaunchKernelGGL(prep_kernel, dim3(NS * NP / 16), dim3(256), 0, stream,
                       h, x2, hh);
    hipLaunchKernelGGL(knn_mfma, dim3(NS * (NP / RB)), dim3(NT), 0, stream,
                       h, hh, x2, out);
}

// Round 11
// 223.612 us; speedup vs baseline: 1.0559x; 1.0559x over previous
//
#include <hip/hip_runtime.h>
#include <hip/hip_fp16.h>
#include <cfloat>

// NearestNeighborGraph: S=16, N=2048, D=64, K=16.
// Round-19: 1.5-pass scan, register-pressure fix.
//  r18 post-mortem: knn 160->181us with WRITE 24.6->89MB, FETCH 15.7->47MB
//  -> scratch spill in A2 (PF=4 pipeline regs + fold + push live at once).
//  r12==r13 already proved the explicit PF pipeline is worthless here
//  (162 vs 160us). Fix: delete it everywhere; plain unroll-2 loops load
//  jlo/jhi/xq inline (transient ~10 VGPR vs 40). Algorithm unchanged from
//  r18 (passed):
//   A1 (tiles 0-15): fold-only -> tau0 = max_w(4th-of-256) + MARGIN.
//   A2 (tiles 16-31): fold + push d2' < tau0.
//   final merge -> tau_final (fold order == r16 -> bit-identical).
//   B' (tiles 0-15): push d2' < tau_final.
//   rescue: exact fp32 ring recompute; if rcnt > RCAP (P~1e-14) the row's
//   workers brute-force all 2048 j's exactly -> correctness unconditional.
//  Scan volume: 48 tiles/wave vs r16's 64 (0.75x).

typedef _Float16 half8 __attribute__((ext_vector_type(8)));
typedef _Float16 half4 __attribute__((ext_vector_type(4)));
typedef float    f32x4 __attribute__((ext_vector_type(4)));

constexpr int NS = 16, NP = 2048, ND = 64, KK = 16;
constexpr int NWV = 4;              // waves per block
constexpr int NT  = NWV * 64;       // 256 threads
constexpr int RB  = 32;             // rows (i) per block
constexpr int ITN = RB / 16;        // 2 i-tiles
constexpr int JW  = NP / NWV;       // 512 j per wave
constexpr int NJT = JW / 16;        // 32 j-tiles per wave
constexpr int NJT0 = 16;            // prefix tiles (tau0 seed + B' rescan)
constexpr int MS  = 17;             // merge-tree stride
constexpr int RCAP = 176;           // candidate ring slots per row
constexpr int RSTR = RCAP + 1;      // ring stride
constexpr float MARGIN = 1.0f;

// ---- prep: 16 rows/block; coalesced f16 copy + rotated-chain x2 ----
__global__ __launch_bounds__(256)
void prep_kernel(const float* __restrict__ h, float* __restrict__ x2,
                 _Float16* __restrict__ hh)
{
    const int b = blockIdx.x;                 // 0..2047, 16 rows each
    const int t = threadIdx.x;
    const size_t base = (size_t)b * 16 * ND;  // flat float offset

    // f16 conversion: thread t -> elements [base + 4t, base + 4t + 4)
    float4 v = *(const float4*)(h + base + (size_t)t * 4);
    half4 p;
    p[0] = (_Float16)v.x; p[1] = (_Float16)v.y;
    p[2] = (_Float16)v.z; p[3] = (_Float16)v.w;
    *(half4*)(hh + base + (size_t)t * 4) = p;

    // x2: rotated chain, bit-identical to rounds 1-18 (1 thread per row)
    if (t < 16) {
        const int g = b * 16 + t;             // flat row
        const float4* row = (const float4*)(h + (size_t)g * ND);
        const int ph = g & 15;
        float a0 = 0.f, a1 = 0.f, a2 = 0.f, a3 = 0.f;
        #pragma unroll
        for (int k = 0; k < 16; ++k) {
            float4 u = row[(k + ph) & 15];
            a0 = fmaf(u.x, u.x, a0); a1 = fmaf(u.y, u.y, a1);
            a2 = fmaf(u.z, u.z, a2); a3 = fmaf(u.w, u.w, a3);
        }
        x2[g] = (a0 + a1) + (a2 + a3);
    }
}

// lexicographic (d2, j) insert == top_k tie-break (lowest index on equal d2)
__device__ __forceinline__ bool lexlt(float a, int ja, float b, int jb)
{
    return (a < b) || (a == b && ja < jb);
}
__device__ __forceinline__ void insert16x(float (&d)[KK], int (&ix)[KK],
                                          float v, int j)
{
    #pragma unroll
    for (int p = KK - 1; p > 0; --p) {
        bool sh = lexlt(v, j, d[p - 1], ix[p - 1]);
        bool he = lexlt(v, j, d[p], ix[p]);
        float nd = sh ? d[p - 1] : (he ? v : d[p]);
        int   ni = sh ? ix[p - 1] : (he ? j : ix[p]);
        d[p] = nd; ix[p] = ni;
    }
    if (lexlt(v, j, d[0], ix[0])) { d[0] = v; ix[0] = j; }
}

// in-place bitonic merge of two sorted-4 lists across lane-xor 'mask'
__device__ __forceinline__ void bitonic4(float &a1, float &a2, float &a3,
                                         float &a4, int mask)
{
    float b1 = __shfl_xor(a1, mask), b2 = __shfl_xor(a2, mask);
    float b3 = __shfl_xor(a3, mask), b4 = __shfl_xor(a4, mask);
    float m1 = fminf(a1, b4), m2 = fminf(a2, b3);
    float m3 = fminf(a3, b2), m4 = fminf(a4, b1);
    float u1 = fminf(m1, m3), u3 = fmaxf(m1, m3);
    float u2 = fminf(m2, m4), u4 = fmaxf(m2, m4);
    a1 = fminf(u1, u2); a2 = fmaxf(u1, u2);
    a3 = fminf(u3, u4); a4 = fmaxf(u3, u4);
}

__global__ __launch_bounds__(NT, 4)
void knn_mfma(const float* __restrict__ h, const _Float16* __restrict__ hh,
              const float* __restrict__ x2g, float* __restrict__ out)
{
    // 10080 floats = 40320 B -> 4 blocks/CU
    __shared__ __align__(16) float smem[10080];
    float* ldsx2  = smem;                    // [0,2048)
    float* mw     = smem + 2048;             // [2048,2176)  4 waves x 32 rows
    float* ldsthr = smem + 2176;             // [2176,2208)
    int*   rcnt   = (int*)(smem + 2208);     // [2208,2240)
    int*   ring   = (int*)(smem + 2240);     // [2240,7904)  32 x 177
    float* md     = smem + 7904;             // [7904,8992)  2 x 32 x 17
    int*   mi     = (int*)(smem + 8992);     // [8992,10080)

    const int t   = threadIdx.x;
    const int ln  = t & 63;
    const int qd  = ln >> 4;                 // j-subslice within wave
    const int cl  = ln & 15;                 // i within 16-tile (swapped D col)
    const int q   = t >> 6;                  // wave id (j-quarter)
    const int row = ln & 31;                 // lane's rescue row
    const int jh  = ln >> 5;                 // rescue worker split
    // XCD sample-affinity swizzle (bijective): sample s -> XCD (s&7),
    // assuming hardware round-robin bid->XCD bid%8 (perf heuristic only).
    const int bid = blockIdx.x;
    const int xcd = bid & 7;
    const int kb  = bid >> 3;                // 0..127
    const int s   = xcd + ((kb & 1) << 3);   // 0..15
    const int rb  = kb >> 1;                 // 0..63
    const int rowbase = rb * RB;             // block's 32 i-rows (sample-local)
    const float*    __restrict__ hs  = h  + (size_t)s * NP * ND;
    const _Float16* __restrict__ hhs = hh + (size_t)s * NP * ND;

    // stage sample x2; init ring counts
    ((float4*)ldsx2)[t]       = ((const float4*)(x2g + s * NP))[t];
    ((float4*)ldsx2)[t + 256] = ((const float4*)(x2g + s * NP))[t + 256];
    if (t < RB) rcnt[t] = 0;

    // i-fragments (the MFMA *B* operand): lane holds I[n=cl][k=qd*8..+7]
    half8 ifr[ITN][2];
    #pragma unroll
    for (int it = 0; it < ITN; ++it) {
        const _Float16* ap = hhs + (size_t)(rowbase + it * 16 + cl) * ND + qd * 8;
        ifr[it][0] = *(const half8*)(ap);
        ifr[it][1] = *(const half8*)(ap + 32);
    }
    __syncthreads();

    const int jbase = q * JW;
    const _Float16* __restrict__ jrow0 = hhs + (size_t)(jbase + cl) * ND + qd * 8;

    // fold state: per-lane sorted top-4 of d2' = x2j - 2*dot
    float t1[ITN], t2[ITN], t3[ITN], t4[ITN];
    #pragma unroll
    for (int it = 0; it < ITN; ++it)
        { t1[it] = FLT_MAX; t2[it] = FLT_MAX; t3[it] = FLT_MAX; t4[it] = FLT_MAX; }
    float thrv[ITN];

    // ===== A1: tiles [0, NJT0) — fold only ==================================
    #pragma unroll 2
    for (int jt = 0; jt < NJT0; ++jt) {
        const _Float16* bp = jrow0 + (size_t)jt * (16 * ND);
        half8 jlo = *(const half8*)(bp);
        half8 jhi = *(const half8*)(bp + 32);
        f32x4 xq = *(const f32x4*)(ldsx2 + jbase + jt * 16 + qd * 4);

        #pragma unroll
        for (int it = 0; it < ITN; ++it) {
            f32x4 acc;
            acc = __builtin_amdgcn_mfma_f32_16x16x32_f16(
                      jlo, ifr[it][0], (f32x4){0.f, 0.f, 0.f, 0.f}, 0, 0, 0);
            acc = __builtin_amdgcn_mfma_f32_16x16x32_f16(
                      jhi, ifr[it][1], acc, 0, 0, 0);
            #pragma unroll
            for (int r = 0; r < 4; ++r) {
                float v  = fmaf(-2.f, acc[r], xq[r]);
                float n1 = fminf(t1[it], v);
                float n2 = __builtin_amdgcn_fmed3f(t1[it], t2[it], v);
                float n3 = __builtin_amdgcn_fmed3f(t2[it], t3[it], v);
                float n4 = __builtin_amdgcn_fmed3f(t3[it], t4[it], v);
                t1[it] = n1; t2[it] = n2; t3[it] = n3; t4[it] = n4;
            }
        }
    }

    // ---- mid-merge on COPIES (fold regs untouched) -> tau0 ----
    {
        float c1[ITN], c2[ITN], c3[ITN], c4[ITN];
        #pragma unroll
        for (int it = 0; it < ITN; ++it)
            { c1[it] = t1[it]; c2[it] = t2[it]; c3[it] = t3[it]; c4[it] = t4[it]; }
        #pragma unroll
        for (int it = 0; it < ITN; ++it) {
            bitonic4(c1[it], c2[it], c3[it], c4[it], 16);
            bitonic4(c1[it], c2[it], c3[it], c4[it], 32);
        }
        if (qd == 0) {
            mw[q * 32 + cl]      = c4[0];   // exact 4th of wave's 256-prefix
            mw[q * 32 + 16 + cl] = c4[1];
        }
    }
    __syncthreads();
    if (q == 0 && ln < 32) {
        float m0 = mw[row], m1 = mw[32 + row];
        float m2 = mw[64 + row], m3 = mw[96 + row];
        ldsthr[row] = fmaxf(fmaxf(m0, m1), fmaxf(m2, m3)) + MARGIN;  // tau0
    }
    __syncthreads();
    #pragma unroll
    for (int it = 0; it < ITN; ++it) thrv[it] = ldsthr[it * 16 + cl];

    // ===== A2: tiles [NJT0, NJT) — fold + push d2' < tau0 ===================
    #pragma unroll 2
    for (int jt = NJT0; jt < NJT; ++jt) {
        const _Float16* bp = jrow0 + (size_t)jt * (16 * ND);
        half8 jlo = *(const half8*)(bp);
        half8 jhi = *(const half8*)(bp + 32);
        f32x4 xq = *(const f32x4*)(ldsx2 + jbase + jt * 16 + qd * 4);
        const int j0 = jbase + jt * 16;

        #pragma unroll
        for (int it = 0; it < ITN; ++it) {
            f32x4 acc;
            acc = __builtin_amdgcn_mfma_f32_16x16x32_f16(
                      jlo, ifr[it][0], (f32x4){0.f, 0.f, 0.f, 0.f}, 0, 0, 0);
            acc = __builtin_amdgcn_mfma_f32_16x16x32_f16(
                      jhi, ifr[it][1], acc, 0, 0, 0);
            #pragma unroll
            for (int r = 0; r < 4; ++r) {
                float v  = fmaf(-2.f, acc[r], xq[r]);
                if (v < thrv[it]) {
                    int rw = it * 16 + cl;
                    int slot = atomicAdd(&rcnt[rw], 1);
                    if (slot < RCAP) ring[rw * RSTR + slot] = j0 + qd * 4 + r;
                }
                float n1 = fminf(t1[it], v);
                float n2 = __builtin_amdgcn_fmed3f(t1[it], t2[it], v);
                float n3 = __builtin_amdgcn_fmed3f(t2[it], t3[it], v);
                float n4 = __builtin_amdgcn_fmed3f(t3[it], t4[it], v);
                t1[it] = n1; t2[it] = n2; t3[it] = n3; t4[it] = n4;
            }
        }
    }

    // ---- final merge (destructive, == r16) -> tau_final ----
    #pragma unroll
    for (int it = 0; it < ITN; ++it) {
        bitonic4(t1[it], t2[it], t3[it], t4[it], 16);
        bitonic4(t1[it], t2[it], t3[it], t4[it], 32);
    }
    if (qd == 0) {
        mw[q * 32 + cl]      = t4[0];   // exact 4th of wave's 512
        mw[q * 32 + 16 + cl] = t4[1];
    }
    __syncthreads();
    if (q == 0 && ln < 32) {
        float m0 = mw[row], m1 = mw[32 + row];
        float m2 = mw[64 + row], m3 = mw[96 + row];
        ldsthr[row] = fmaxf(fmaxf(m0, m1), fmaxf(m2, m3)) + MARGIN;  // tau
    }
    __syncthreads();
    #pragma unroll
    for (int it = 0; it < ITN; ++it) thrv[it] = ldsthr[it * 16 + cl];

    // ===== B': re-scan tiles [0, NJT0) — push d2' < tau_final ===============
    #pragma unroll 2
    for (int jt = 0; jt < NJT0; ++jt) {
        const _Float16* bp = jrow0 + (size_t)jt * (16 * ND);
        half8 jlo = *(const half8*)(bp);
        half8 jhi = *(const half8*)(bp + 32);
        f32x4 xq = *(const f32x4*)(ldsx2 + jbase + jt * 16 + qd * 4);
        const int j0 = jbase + jt * 16;

        #pragma unroll
        for (int it = 0; it < ITN; ++it) {
            f32x4 acc;
            acc = __builtin_amdgcn_mfma_f32_16x16x32_f16(
                      jlo, ifr[it][0], (f32x4){0.f, 0.f, 0.f, 0.f}, 0, 0, 0);
            acc = __builtin_amdgcn_mfma_f32_16x16x32_f16(
                      jhi, ifr[it][1], acc, 0, 0, 0);
            #pragma unroll
            for (int r = 0; r < 4; ++r) {
                float d2 = fmaf(-2.f, acc[r], xq[r]);
                if (d2 < thrv[it]) {
                    int rw = it * 16 + cl;
                    int slot = atomicAdd(&rcnt[rw], 1);
                    if (slot < RCAP) ring[rw * RSTR + slot] = j0 + qd * 4 + r;
                }
            }
        }
    }
    __syncthreads();

    // ========== rescue: exact fp32 recompute of candidates ===============
    // row = ln&31; 8 workers per row: (wave q, half jh) take slots w8, w8+8,...
    const int myrow = rowbase + row;
    float4 A[16];
    {
        const float4* ra = (const float4*)(hs + (size_t)myrow * ND);
        #pragma unroll
        for (int k = 0; k < 16; ++k) A[k] = ra[k];
    }
    float x2i;   // ascending chain (exact round-1 i-side value)
    {
        float a0 = 0.f, a1 = 0.f, a2 = 0.f, a3 = 0.f;
        #pragma unroll
        for (int k = 0; k < 16; ++k) {
            a0 = fmaf(A[k].x, A[k].x, a0); a1 = fmaf(A[k].y, A[k].y, a1);
            a2 = fmaf(A[k].z, A[k].z, a2); a3 = fmaf(A[k].w, A[k].w, a3);
        }
        x2i = (a0 + a1) + (a2 + a3);
    }
    float dist[KK]; int idx[KK];
    #pragma unroll
    for (int k = 0; k < KK; ++k) { dist[k] = FLT_MAX; idx[k] = 0; }

    const int rawc = rcnt[row];
    const int w8 = q * 2 + jh;
    if (rawc <= RCAP) {
        // normal path: exact recompute of ring candidates
        #pragma unroll 1
        for (int k = w8; k < rawc; k += 8) {
            int j = ring[row * RSTR + k];
            const float4* cv = (const float4*)(hs + (size_t)j * ND);
            float a0 = 0.f, a1 = 0.f, a2 = 0.f, a3 = 0.f;
            #pragma unroll
            for (int kk = 0; kk < 16; ++kk) {
                float4 c = cv[kk];
                a0 = fmaf(A[kk].x, c.x, a0); a1 = fmaf(A[kk].y, c.y, a1);
                a2 = fmaf(A[kk].z, c.z, a2); a3 = fmaf(A[kk].w, c.w, a3);
            }
            float dotv = (a0 + a1) + (a2 + a3);
            float d2 = fmaf(-2.0f, dotv, x2i + ldsx2[j]);
            if (lexlt(d2, j, dist[KK - 1], idx[KK - 1]))
                insert16x(dist, idx, d2, j);
        }
    } else {
        // overflow fallback (P ~ 1e-14/row): ring is incomplete -> exact
        // brute-force of the full row (reference by construction). Ring
        // entries are SKIPPED entirely (mixing would double-insert).
        #pragma unroll 1
        for (int j = w8; j < NP; j += 8) {
            const float4* cv = (const float4*)(hs + (size_t)j * ND);
            float a0 = 0.f, a1 = 0.f, a2 = 0.f, a3 = 0.f;
            #pragma unroll
            for (int kk = 0; kk < 16; ++kk) {
                float4 c = cv[kk];
                a0 = fmaf(A[kk].x, c.x, a0); a1 = fmaf(A[kk].y, c.y, a1);
                a2 = fmaf(A[kk].z, c.z, a2); a3 = fmaf(A[kk].w, c.w, a3);
            }
            float dotv = (a0 + a1) + (a2 + a3);
            float d2 = fmaf(-2.0f, dotv, x2i + ldsx2[j]);
            if (lexlt(d2, j, dist[KK - 1], idx[KK - 1]))
                insert16x(dist, idx, d2, j);
        }
    }

    // ---- final exact merge (lex): shuffle level + 2 LDS levels (gated) ----
    #pragma unroll 1
    for (int k = 0; k < KK; ++k) {
        float v  = __shfl(dist[k], row + 32);
        int   jv = __shfl(idx[k],  row + 32);
        bool need = (ln < 32) && lexlt(v, jv, dist[KK - 1], idx[KK - 1]);
        if (!__any(need)) break;
        if (need) insert16x(dist, idx, v, jv);
    }
    __syncthreads();
    #pragma unroll 1
    for (int lvl = 0; lvl < 2; ++lvl) {
        const int step = 1 << lvl;
        const int m    = (step << 1) - 1;
        const bool pub = ((q & m) == step) && ln < 32;
        const int reg  = q >> (lvl + 1);
        if (pub) {
            #pragma unroll
            for (int k = 0; k < KK; ++k) {
                md[(reg * RB + row) * MS + k] = dist[k];
                mi[(reg * RB + row) * MS + k] = idx[k];
            }
        }
        __syncthreads();
        if ((q & m) == 0) {
            #pragma unroll 1
            for (int k = 0; k < KK; ++k) {
                float v  = md[(reg * RB + row) * MS + k];
                int   jv = mi[(reg * RB + row) * MS + k];
                bool need = (ln < 32) && lexlt(v, jv, dist[KK - 1], idx[KK - 1]);
                if (!__any(need)) break;
                if (need) insert16x(dist, idx, v, jv);
            }
        }
        __syncthreads();
    }

    // ---- output (wave 0, lower half) ----
    if (q == 0 && ln < 32) {
        const int off = s * NP;
        const size_t rg = (size_t)off + myrow;
        float* o0 = out + rg * KK;
        float* o1 = out + (size_t)NS * NP * KK + rg * KK;
        float* o2 = out + (size_t)2 * NS * NP * KK + rg * KK;
        #pragma unroll
        for (int k = 0; k < KK; ++k) o0[k] = dist[k];
        #pragma unroll
        for (int k = 0; k < KK; ++k) o1[k] = (float)(idx[k] + off);
        #pragma unroll
        for (int k = 0; k < KK; ++k) o2[k] = (float)(off + myrow);
    }
}

extern "C" void kernel_launch(void* const* d_in, const int* in_sizes, int n_in,
                              void* d_out, int out_size, void* d_ws, size_t ws_size,
                              hipStream_t stream)
{
    const float* h = (const float*)d_in[0];
    float* out = (float*)d_out;
    float*    x2 = (float*)d_ws;                     // 32768 floats (128 KB)
    _Float16* hh = (_Float16*)(x2 + NS * NP);        // 16*2048*64 halves (4 MB)

    hipLaunchKernelGGL(prep_kernel, dim3(NS * NP / 16), dim3(256), 0, stream,
                       h, x2, hh);
    hipLaunchKernelGGL(knn_mfma, dim3(NS * (NP / RB)), dim3(NT), 0, stream,
                       h, hh, x2, out);
}

// Round 12
// 178.153 us; speedup vs baseline: 1.3253x; 1.2552x over previous
//
#include <hip/hip_runtime.h>
#include <hip/hip_fp16.h>
#include <cfloat>

// NearestNeighborGraph: S=16, N=2048, D=64, K=16.
// Round-20: r16's 2-pass structure with RB=64 (ITN=4) -> j-traffic halved.
//  r19 post-mortem: 25% fewer tiles but 3-phase overhead made it WORSE
//  (173 vs 160) -> r16 2-phase is the right schedule. Surviving model for
//  the 160us floor: cache-delivery bandwidth at low effective clock —
//  every block streams its sample's full j-space twice (512MB L2 total).
//  Fix: 64-row blocks amortize each j-fragment load over 4 i-tiles
//  (512 blocks x 4 waves x 64 tiles x 2KB = 256MB, 0.5x).
//  tau math per (row, wave-512-substream) unchanged -> bit-identical tau,
//  rings, exact fp32 rescue -> output identical to r16 (passed).
//  LDS 72.4KB -> 2 blocks/CU (occupancy proven irrelevant, r10).
//  Rescue: 4 workers/row (row = ln, wave q strides 4); overflow fallback
//  (full-row exact brute force) retained -> correctness unconditional.

typedef _Float16 half8 __attribute__((ext_vector_type(8)));
typedef _Float16 half4 __attribute__((ext_vector_type(4)));
typedef float    f32x4 __attribute__((ext_vector_type(4)));

constexpr int NS = 16, NP = 2048, ND = 64, KK = 16;
constexpr int NWV = 4;              // waves per block
constexpr int NT  = NWV * 64;       // 256 threads
constexpr int RB  = 64;             // rows (i) per block
constexpr int ITN = RB / 16;        // 4 i-tiles
constexpr int JW  = NP / NWV;       // 512 j per wave
constexpr int NJT = JW / 16;        // 32 j-tiles per wave
constexpr int MS  = 17;             // merge-tree stride
constexpr int RCAP = 176;           // candidate ring slots per row
constexpr int RSTR = RCAP + 1;      // ring stride
constexpr float MARGIN = 1.0f;

// ---- prep: 16 rows/block; coalesced f16 copy + rotated-chain x2 ----
__global__ __launch_bounds__(256)
void prep_kernel(const float* __restrict__ h, float* __restrict__ x2,
                 _Float16* __restrict__ hh)
{
    const int b = blockIdx.x;                 // 0..2047, 16 rows each
    const int t = threadIdx.x;
    const size_t base = (size_t)b * 16 * ND;  // flat float offset

    // f16 conversion: thread t -> elements [base + 4t, base + 4t + 4)
    float4 v = *(const float4*)(h + base + (size_t)t * 4);
    half4 p;
    p[0] = (_Float16)v.x; p[1] = (_Float16)v.y;
    p[2] = (_Float16)v.z; p[3] = (_Float16)v.w;
    *(half4*)(hh + base + (size_t)t * 4) = p;

    // x2: rotated chain, bit-identical to rounds 1-19 (1 thread per row)
    if (t < 16) {
        const int g = b * 16 + t;             // flat row
        const float4* row = (const float4*)(h + (size_t)g * ND);
        const int ph = g & 15;
        float a0 = 0.f, a1 = 0.f, a2 = 0.f, a3 = 0.f;
        #pragma unroll
        for (int k = 0; k < 16; ++k) {
            float4 u = row[(k + ph) & 15];
            a0 = fmaf(u.x, u.x, a0); a1 = fmaf(u.y, u.y, a1);
            a2 = fmaf(u.z, u.z, a2); a3 = fmaf(u.w, u.w, a3);
        }
        x2[g] = (a0 + a1) + (a2 + a3);
    }
}

// lexicographic (d2, j) insert == top_k tie-break (lowest index on equal d2)
__device__ __forceinline__ bool lexlt(float a, int ja, float b, int jb)
{
    return (a < b) || (a == b && ja < jb);
}
__device__ __forceinline__ void insert16x(float (&d)[KK], int (&ix)[KK],
                                          float v, int j)
{
    #pragma unroll
    for (int p = KK - 1; p > 0; --p) {
        bool sh = lexlt(v, j, d[p - 1], ix[p - 1]);
        bool he = lexlt(v, j, d[p], ix[p]);
        float nd = sh ? d[p - 1] : (he ? v : d[p]);
        int   ni = sh ? ix[p - 1] : (he ? j : ix[p]);
        d[p] = nd; ix[p] = ni;
    }
    if (lexlt(v, j, d[0], ix[0])) { d[0] = v; ix[0] = j; }
}

// in-place bitonic merge of two sorted-4 lists across lane-xor 'mask'
__device__ __forceinline__ void bitonic4(float &a1, float &a2, float &a3,
                                         float &a4, int mask)
{
    float b1 = __shfl_xor(a1, mask), b2 = __shfl_xor(a2, mask);
    float b3 = __shfl_xor(a3, mask), b4 = __shfl_xor(a4, mask);
    float m1 = fminf(a1, b4), m2 = fminf(a2, b3);
    float m3 = fminf(a3, b2), m4 = fminf(a4, b1);
    float u1 = fminf(m1, m3), u3 = fmaxf(m1, m3);
    float u2 = fminf(m2, m4), u4 = fmaxf(m2, m4);
    a1 = fminf(u1, u2); a2 = fmaxf(u1, u2);
    a3 = fminf(u3, u4); a4 = fmaxf(u3, u4);
}

__global__ __launch_bounds__(NT, 2)
void knn_mfma(const float* __restrict__ h, const _Float16* __restrict__ hh,
              const float* __restrict__ x2g, float* __restrict__ out)
{
    // 18112 floats = 72448 B -> 2 blocks/CU
    __shared__ __align__(16) float smem[18112];
    float* ldsx2  = smem;                    // [0,2048)
    float* mw     = smem + 2048;             // [2048,2304)   4 waves x 64 rows
    float* ldsthr = smem + 2304;             // [2304,2368)
    int*   rcnt   = (int*)(smem + 2368);     // [2368,2432)
    int*   ring   = (int*)(smem + 2432);     // [2432,13760)  64 x 177
    float* md     = smem + 13760;            // [13760,15936) 2 x 64 x 17
    int*   mi     = (int*)(smem + 15936);    // [15936,18112)

    const int t   = threadIdx.x;
    const int ln  = t & 63;
    const int qd  = ln >> 4;                 // j-subslice within wave
    const int cl  = ln & 15;                 // i within 16-tile (swapped D col)
    const int q   = t >> 6;                  // wave id (j-quarter)
    // XCD sample-affinity swizzle (bijective): sample s -> XCD (s&7),
    // assuming hardware round-robin bid->XCD bid%8 (perf heuristic only).
    const int bid = blockIdx.x;              // 0..511
    const int xcd = bid & 7;
    const int kb  = bid >> 3;                // 0..63
    const int s   = xcd + ((kb & 1) << 3);   // 0..15
    const int rb  = kb >> 1;                 // 0..31
    const int rowbase = rb * RB;             // block's 64 i-rows (sample-local)
    const float*    __restrict__ hs  = h  + (size_t)s * NP * ND;
    const _Float16* __restrict__ hhs = hh + (size_t)s * NP * ND;

    // stage sample x2; init ring counts
    ((float4*)ldsx2)[t]       = ((const float4*)(x2g + s * NP))[t];
    ((float4*)ldsx2)[t + 256] = ((const float4*)(x2g + s * NP))[t + 256];
    if (t < RB) rcnt[t] = 0;

    // i-fragments (the MFMA *B* operand): lane holds I[n=cl][k=qd*8..+7]
    half8 ifr[ITN][2];
    #pragma unroll
    for (int it = 0; it < ITN; ++it) {
        const _Float16* ap = hhs + (size_t)(rowbase + it * 16 + cl) * ND + qd * 8;
        ifr[it][0] = *(const half8*)(ap);
        ifr[it][1] = *(const half8*)(ap + 32);
    }
    __syncthreads();

    const int jbase = q * JW;
    const _Float16* __restrict__ jrow0 = hhs + (size_t)(jbase + cl) * ND + qd * 8;

    // fold state: per-lane sorted top-4 of d2' = x2j - 2*dot, per i-tile
    float t1[ITN], t2[ITN], t3[ITN], t4[ITN];
    #pragma unroll
    for (int it = 0; it < ITN; ++it)
        { t1[it] = FLT_MAX; t2[it] = FLT_MAX; t3[it] = FLT_MAX; t4[it] = FLT_MAX; }

    // ===== stage A: fold-only scan (32 tiles, 4 i-tiles per j-load) =========
    #pragma unroll 2
    for (int jt = 0; jt < NJT; ++jt) {
        const _Float16* bp = jrow0 + (size_t)jt * (16 * ND);
        half8 jlo = *(const half8*)(bp);
        half8 jhi = *(const half8*)(bp + 32);
        f32x4 xq = *(const f32x4*)(ldsx2 + jbase + jt * 16 + qd * 4);

        #pragma unroll
        for (int it = 0; it < ITN; ++it) {
            f32x4 acc;
            acc = __builtin_amdgcn_mfma_f32_16x16x32_f16(
                      jlo, ifr[it][0], (f32x4){0.f, 0.f, 0.f, 0.f}, 0, 0, 0);
            acc = __builtin_amdgcn_mfma_f32_16x16x32_f16(
                      jhi, ifr[it][1], acc, 0, 0, 0);
            #pragma unroll
            for (int r = 0; r < 4; ++r) {
                float v  = fmaf(-2.f, acc[r], xq[r]);
                float n1 = fminf(t1[it], v);
                float n2 = __builtin_amdgcn_fmed3f(t1[it], t2[it], v);
                float n3 = __builtin_amdgcn_fmed3f(t2[it], t3[it], v);
                float n4 = __builtin_amdgcn_fmed3f(t3[it], t4[it], v);
                t1[it] = n1; t2[it] = n2; t3[it] = n3; t4[it] = n4;
            }
        }
    }

    // merge the 4 qd sub-lists (sorted 4s) -> wave's exact top-4 of 512
    #pragma unroll
    for (int it = 0; it < ITN; ++it) {
        bitonic4(t1[it], t2[it], t3[it], t4[it], 16);
        bitonic4(t1[it], t2[it], t3[it], t4[it], 32);
    }
    if (qd == 0) {
        #pragma unroll
        for (int it = 0; it < ITN; ++it)
            mw[q * RB + it * 16 + cl] = t4[it];   // 4th of wave's 512, row
    }
    __syncthreads();
    // tau = max over 4 waves of (exact 4th of 512-substream) + margin
    if (q == 0) {
        float m0 = mw[ln],            m1 = mw[RB + ln];
        float m2 = mw[2 * RB + ln],   m3 = mw[3 * RB + ln];
        ldsthr[ln] = fmaxf(fmaxf(m0, m1), fmaxf(m2, m3)) + MARGIN;
    }
    __syncthreads();

    // tau for lane's 4 i-rows
    float thrv[ITN];
    #pragma unroll
    for (int it = 0; it < ITN; ++it) thrv[it] = ldsthr[it * 16 + cl];

    // ===== stage B: re-scan, filter d2' < tau into candidate rings ==========
    #pragma unroll 2
    for (int jt = 0; jt < NJT; ++jt) {
        const _Float16* bp = jrow0 + (size_t)jt * (16 * ND);
        half8 jlo = *(const half8*)(bp);
        half8 jhi = *(const half8*)(bp + 32);
        f32x4 xq = *(const f32x4*)(ldsx2 + jbase + jt * 16 + qd * 4);
        const int j0 = jbase + jt * 16;

        #pragma unroll
        for (int it = 0; it < ITN; ++it) {
            f32x4 acc;
            acc = __builtin_amdgcn_mfma_f32_16x16x32_f16(
                      jlo, ifr[it][0], (f32x4){0.f, 0.f, 0.f, 0.f}, 0, 0, 0);
            acc = __builtin_amdgcn_mfma_f32_16x16x32_f16(
                      jhi, ifr[it][1], acc, 0, 0, 0);
            #pragma unroll
            for (int r = 0; r < 4; ++r) {
                float d2 = fmaf(-2.f, acc[r], xq[r]);
                if (d2 < thrv[it]) {
                    int rw = it * 16 + cl;
                    int slot = atomicAdd(&rcnt[rw], 1);
                    if (slot < RCAP) ring[rw * RSTR + slot] = j0 + qd * 4 + r;
                }
            }
        }
    }
    __syncthreads();

    // ========== rescue: exact fp32 recompute of candidates ===============
    // row = ln (0..63); 4 workers per row: wave q takes slots q, q+4, ...
    const int row   = ln;
    const int myrow = rowbase + row;
    float4 A[16];
    {
        const float4* ra = (const float4*)(hs + (size_t)myrow * ND);
        #pragma unroll
        for (int k = 0; k < 16; ++k) A[k] = ra[k];
    }
    float x2i;   // ascending chain (exact round-1 i-side value)
    {
        float a0 = 0.f, a1 = 0.f, a2 = 0.f, a3 = 0.f;
        #pragma unroll
        for (int k = 0; k < 16; ++k) {
            a0 = fmaf(A[k].x, A[k].x, a0); a1 = fmaf(A[k].y, A[k].y, a1);
            a2 = fmaf(A[k].z, A[k].z, a2); a3 = fmaf(A[k].w, A[k].w, a3);
        }
        x2i = (a0 + a1) + (a2 + a3);
    }
    float dist[KK]; int idx[KK];
    #pragma unroll
    for (int k = 0; k < KK; ++k) { dist[k] = FLT_MAX; idx[k] = 0; }

    const int rawc = rcnt[row];
    if (rawc <= RCAP) {
        // normal path: exact recompute of ring candidates
        #pragma unroll 1
        for (int k = q; k < rawc; k += NWV) {
            int j = ring[row * RSTR + k];
            const float4* cv = (const float4*)(hs + (size_t)j * ND);
            float a0 = 0.f, a1 = 0.f, a2 = 0.f, a3 = 0.f;
            #pragma unroll
            for (int kk = 0; kk < 16; ++kk) {
                float4 c = cv[kk];
                a0 = fmaf(A[kk].x, c.x, a0); a1 = fmaf(A[kk].y, c.y, a1);
                a2 = fmaf(A[kk].z, c.z, a2); a3 = fmaf(A[kk].w, c.w, a3);
            }
            float dotv = (a0 + a1) + (a2 + a3);
            float d2 = fmaf(-2.0f, dotv, x2i + ldsx2[j]);
            if (lexlt(d2, j, dist[KK - 1], idx[KK - 1]))
                insert16x(dist, idx, d2, j);
        }
    } else {
        // overflow fallback (P ~ 1e-14/row): ring is incomplete -> exact
        // brute-force of the full row (reference by construction). Ring
        // entries are SKIPPED entirely (mixing would double-insert).
        #pragma unroll 1
        for (int j = q; j < NP; j += NWV) {
            const float4* cv = (const float4*)(hs + (size_t)j * ND);
            float a0 = 0.f, a1 = 0.f, a2 = 0.f, a3 = 0.f;
            #pragma unroll
            for (int kk = 0; kk < 16; ++kk) {
                float4 c = cv[kk];
                a0 = fmaf(A[kk].x, c.x, a0); a1 = fmaf(A[kk].y, c.y, a1);
                a2 = fmaf(A[kk].z, c.z, a2); a3 = fmaf(A[kk].w, c.w, a3);
            }
            float dotv = (a0 + a1) + (a2 + a3);
            float d2 = fmaf(-2.0f, dotv, x2i + ldsx2[j]);
            if (lexlt(d2, j, dist[KK - 1], idx[KK - 1]))
                insert16x(dist, idx, d2, j);
        }
    }

    // ---- final exact merge (lex): 2 LDS levels (gated) ----
    __syncthreads();
    #pragma unroll 1
    for (int lvl = 0; lvl < 2; ++lvl) {
        const int step = 1 << lvl;
        const int m    = (step << 1) - 1;
        const bool pub = ((q & m) == step);
        const int reg  = q >> (lvl + 1);
        if (pub) {
            #pragma unroll
            for (int k = 0; k < KK; ++k) {
                md[(reg * RB + row) * MS + k] = dist[k];
                mi[(reg * RB + row) * MS + k] = idx[k];
            }
        }
        __syncthreads();
        if ((q & m) == 0) {
            #pragma unroll 1
            for (int k = 0; k < KK; ++k) {
                float v  = md[(reg * RB + row) * MS + k];
                int   jv = mi[(reg * RB + row) * MS + k];
                bool need = lexlt(v, jv, dist[KK - 1], idx[KK - 1]);
                if (!__any(need)) break;
                if (need) insert16x(dist, idx, v, jv);
            }
        }
        __syncthreads();
    }

    // ---- output (wave 0) ----
    if (q == 0) {
        const int off = s * NP;
        const size_t rg = (size_t)off + myrow;
        float* o0 = out + rg * KK;
        float* o1 = out + (size_t)NS * NP * KK + rg * KK;
        float* o2 = out + (size_t)2 * NS * NP * KK + rg * KK;
        #pragma unroll
        for (int k = 0; k < KK; ++k) o0[k] = dist[k];
        #pragma unroll
        for (int k = 0; k < KK; ++k) o1[k] = (float)(idx[k] + off);
        #pragma unroll
        for (int k = 0; k < KK; ++k) o2[k] = (float)(off + myrow);
    }
}

extern "C" void kernel_launch(void* const* d_in, const int* in_sizes, int n_in,
                              void* d_out, int out_size, void* d_ws, size_t ws_size,
                              hipStream_t stream)
{
    const float* h = (const float*)d_in[0];
    float* out = (float*)d_out;
    float*    x2 = (float*)d_ws;                     // 32768 floats (128 KB)
    _Float16* hh = (_Float16*)(x2 + NS * NP);        // 16*2048*64 halves (4 MB)

    hipLaunchKernelGGL(prep_kernel, dim3(NS * NP / 16), dim3(256), 0, stream,
                       h, x2, hh);
    hipLaunchKernelGGL(knn_mfma, dim3(NS * (NP / RB)), dim3(NT), 0, stream,
                       h, hh, x2, out);
}